// Round 1
// baseline (3506.561 us; speedup 1.0000x reference)
//
#include <hip/hip_runtime.h>

// ============================================================================
// Bidirectional LSTM encoder, MI355X.
// Design (R1):
//   prep kernels: gather emb->bf16 A [8192,320]; W->bf16 [4096col'][320] (col'
//     = dir*2048 + unit*4 + gate, K-major transposed); U likewise [4096][512];
//     mask bitmap; h0 -> A-fragment image.
//   k_ingemm: bf16 MFMA 16x16x32, xW+b -> bf16 [8192 rows(t*32+b)][4096].
//   k_recur: persistent, 256 wgs x 512thr. 8 sync groups x 32 wgs.
//     groups 0-3 = fwd replicas, 4-7 = bwd replicas (XCD-local sync heuristic,
//     agent-scope correctness). Per wg: 64 z-cols, U-slice in VGPRs as B-frags.
//     Per step: load h A-frags (global, double-buffered) -> 16 MFMA/wave ->
//     z to LDS -> gate math fp32 -> write h frag + outputs -> fence+arrive.
// ============================================================================

typedef unsigned short u16;
typedef unsigned int   u32;
typedef u16   u16x8 __attribute__((ext_vector_type(8)));
typedef u16   u16x4 __attribute__((ext_vector_type(4)));
typedef __bf16 bf16x8 __attribute__((ext_vector_type(8)));
typedef float f32x4 __attribute__((ext_vector_type(4)));

#define EP 320            // padded E (300 -> 320)
#define NC 4096           // 2 dirs * 4H

static const size_t OFF_AEMB = 0;                              // 8192*320*2 = 5,242,880
static const size_t OFF_WPT  = OFF_AEMB + (size_t)8192*EP*2;
static const size_t OFF_BIAS = OFF_WPT  + (size_t)NC*EP*2;     // f32[4096]
static const size_t OFF_UPT  = OFF_BIAS + (size_t)NC*4;        // bf16 [4096][512]
static const size_t OFF_MASK = OFF_UPT  + (size_t)NC*512*2;    // u32 [32][8]
static const size_t OFF_HFRG = OFF_MASK + 1024;                // bf16 8grp*[2par][2mt][16ks][64][8]
static const size_t OFF_CNT  = OFF_HFRG + (size_t)8*32768*2;   // u32 [8][256]
static const size_t OFF_XW   = OFF_CNT  + 8192;                // bf16 [8192][4096] = 67,108,864
// total = 79,717,376 bytes

__device__ __forceinline__ u16 f2bf(float f){               // RNE: biased trunc would drift the recurrence
  u32 u = __builtin_bit_cast(u32, f);
  return (u16)((u + 0x7FFFu + ((u >> 16) & 1u)) >> 16);
}
__device__ __forceinline__ float bf2f(u16 h){
  u32 u = ((u32)h) << 16; return __builtin_bit_cast(float, u);
}
__device__ __forceinline__ float sigm(float x){ return 1.f/(1.f+__expf(-x)); }
__device__ __forceinline__ float tanh_(float x){ return 2.f/(1.f+__expf(-2.f*x)) - 1.f; }

// ---------------------------------------------------------------- prep: A=emb gather
__global__ __launch_bounds__(320) void k_prep_aemb(const int* __restrict__ x,
                                                   const float* __restrict__ emb,
                                                   u16* __restrict__ aemb){
  int m = blockIdx.x;            // row = t*32 + b
  int k = threadIdx.x;
  int b = m & 31, t = m >> 5;
  int tok = x[b*256 + t];
  float v = (k < 300) ? emb[(size_t)tok*300 + k] : 0.f;
  aemb[(size_t)m*EP + k] = f2bf(v);
}

// ---------------------------------------------------------------- prep: W -> [col'][K] bf16 + bias
__global__ __launch_bounds__(256) void k_prep_wt(const float* __restrict__ Wf, const float* __restrict__ Wb,
                                                 const float* __restrict__ bfv, const float* __restrict__ bbv,
                                                 u16* __restrict__ wpt, float* __restrict__ bias){
  __shared__ u16 lds[320][64];
  int bid = blockIdx.x, tid = threadIdx.x;   // 64 wgs
  int c0 = bid*64; int dir = c0 >> 11;
  const float* W = dir ? Wb : Wf;
  int cl = tid & 63, rr = tid >> 6;
  int ci = (c0 + cl) & 2047; int srccol = (ci & 3)*512 + (ci >> 2);   // col' = u*4+g  <- g*512+u
  for (int kk = 0; kk < 80; kk++){
    int row = kk*4 + rr;
    float v = (row < 300) ? W[(size_t)row*2048 + srccol] : 0.f;
    lds[row][cl] = f2bf(v);
  }
  __syncthreads();
  int cw = tid >> 2, kc = tid & 3;
  #pragma unroll
  for (int j = 0; j < 10; j++){
    u16x8 v;
    #pragma unroll
    for (int e = 0; e < 8; e++) v[e] = lds[kc*80 + j*8 + e][cw];
    *(u16x8*)&wpt[(size_t)(c0+cw)*EP + kc*80 + j*8] = v;
  }
  if (tid < 64){
    int ci2 = (c0 + tid) & 2047; int sc = (ci2 & 3)*512 + (ci2 >> 2);
    bias[c0 + tid] = (dir ? bbv : bfv)[sc];
  }
}

// ---------------------------------------------------------------- prep: U -> [col'][K] bf16
__global__ __launch_bounds__(256) void k_prep_ut(const float* __restrict__ Uf, const float* __restrict__ Ub,
                                                 u16* __restrict__ upt){
  __shared__ u16 lds[512][32];
  int bid = blockIdx.x, tid = threadIdx.x;   // 128 wgs
  int cg0 = bid*32; int dir = cg0 >> 11;
  const float* U = dir ? Ub : Uf;
  int cl = tid & 31, rr = tid >> 5;
  int ci = (cg0 + cl) & 2047; int srccol = (ci & 3)*512 + (ci >> 2);
  for (int kk = 0; kk < 64; kk++){
    int row = kk*8 + rr;
    lds[row][cl] = f2bf(U[(size_t)row*2048 + srccol]);
  }
  __syncthreads();
  int cw = tid >> 3, kc = tid & 7;
  #pragma unroll
  for (int j = 0; j < 8; j++){
    u16x8 v;
    #pragma unroll
    for (int e = 0; e < 8; e++) v[e] = lds[kc*64 + j*8 + e][cw];
    *(u16x8*)&upt[(size_t)(cg0+cw)*512 + kc*64 + j*8] = v;
  }
}

// ---------------------------------------------------------------- prep: mask bitmap + h0 frag image
__global__ __launch_bounds__(256) void k_prep_misc(const int* __restrict__ x,
                                                   const float* __restrict__ h0f, const float* __restrict__ h0b,
                                                   u32* __restrict__ maskb, u16* __restrict__ hfrag){
  int bid = blockIdx.x, tid = threadIdx.x;
  if (bid == 512){
    int b = tid >> 3, w = tid & 7;
    u32 m = 0;
    for (int i = 0; i < 32; i++){ int t = w*32 + i; m |= (u32)(x[b*256 + t] != 0) << i; }
    maskb[b*8 + w] = m;
    return;
  }
  int idx = bid*256 + tid;                      // 0 .. 131071
  int grp = idx >> 14, rem = idx & 16383, b = rem >> 9, ug = rem & 511;
  const float* h0 = (grp >= 4) ? h0b : h0f;
  u16 val = f2bf(h0[b*512 + ug]);
  int mt = b >> 4, ks = ug >> 5, q = (ug >> 3) & 3, j = ug & 7, lane = q*16 + (b & 15);
  // parity 1 holds h_{-1}
  hfrag[(size_t)grp*32768 + ((size_t)(2 + mt)*16 + ks)*512 + lane*8 + j] = val;
}

// ---------------------------------------------------------------- input GEMM: xW+b (bf16 MFMA)
__global__ __launch_bounds__(512) void k_ingemm(const u16* __restrict__ aemb, const u16* __restrict__ wpt,
                                                const float* __restrict__ bias, u16* __restrict__ xw){
  int bx = blockIdx.x, by = blockIdx.y;        // 64 x 64
  int tid = threadIdx.x, lane = tid & 63, wv = tid >> 6;
  int m0 = bx*128 + wv*16;
  u16x8 afr[10];
  const u16* ap = aemb + (size_t)(m0 + (lane & 15))*EP + ((lane >> 4)*8);
  #pragma unroll
  for (int ks = 0; ks < 10; ks++) afr[ks] = *(const u16x8*)(ap + ks*32);
  #pragma unroll
  for (int n = 0; n < 4; n++){
    int colp = by*64 + n*16 + (lane & 15);
    const u16* bp = wpt + (size_t)colp*EP + ((lane >> 4)*8);
    f32x4 acc = {0.f, 0.f, 0.f, 0.f};
    #pragma unroll
    for (int ks = 0; ks < 10; ks++){
      bf16x8 bfr = __builtin_bit_cast(bf16x8, *(const u16x8*)(bp + ks*32));
      acc = __builtin_amdgcn_mfma_f32_16x16x32_bf16(__builtin_bit_cast(bf16x8, afr[ks]), bfr, acc, 0, 0, 0);
    }
    float bv = bias[colp];
    #pragma unroll
    for (int v = 0; v < 4; v++){
      int m = m0 + (lane >> 4)*4 + v;          // C/D: col=lane&15, row=(lane>>4)*4+reg  [m89]
      xw[(size_t)m*NC + colp] = f2bf(acc[v] + bv);
    }
  }
}

// ---------------------------------------------------------------- persistent recurrence
__global__ __launch_bounds__(512) void k_recur(const u16* __restrict__ xw, const u16* __restrict__ upt,
                                               const u32* __restrict__ maskb, u16* __restrict__ hfrag,
                                               u32* __restrict__ cnt,
                                               const float* __restrict__ c0f, const float* __restrict__ c0b,
                                               const float* __restrict__ h0f, const float* __restrict__ h0b,
                                               float* __restrict__ out){
  int bid = blockIdx.x;
  int grp = bid & 7, r = bid >> 3;             // group, rank in group (0..31)
  int dir = grp >> 2, rep = grp & 3;           // direction, replica id
  int tid = threadIdx.x, lane = tid & 63, wv = tid >> 6;
  int nw = wv & 3, kh = wv >> 2;               // wave's N-tile (of 4) and K-half

  __shared__ float zbuf[2][32][64];            // [khalf][b][local col]
  __shared__ float c_s[32][16], h_s[32][16];   // fp32 state for owned units
  __shared__ u32 mk[32][8];

  // U-slice as persistent B-fragments in registers (col = r*64 + nw*16 + lane&15)
  bf16x8 bfr[8];
  {
    const u16* ub = upt + ((size_t)dir*2048 + r*64 + nw*16 + (lane & 15))*512 + ((lane >> 4)*8);
    #pragma unroll
    for (int i = 0; i < 8; i++){ int ks = kh*8 + i; bfr[i] = __builtin_bit_cast(bf16x8, *(const u16x8*)(ub + ks*32)); }
  }
  int b = tid >> 4, u = tid & 15, ug = r*16 + u;
  {
    const float* c0 = dir ? c0b : c0f; const float* h0 = dir ? h0b : h0f;
    c_s[b][u] = c0[b*512 + ug];
    h_s[b][u] = h0[b*512 + ug];
    if (tid < 256) mk[tid >> 3][tid & 7] = maskb[tid];
  }
  u16* hfg = hfrag + (size_t)grp*32768;
  u32* mycnt = cnt + grp*256;
  __syncthreads();

  int t0 = dir ? 255 : 0;
  u16x4 pref = *(const u16x4*)(xw + (size_t)(t0*32 + b)*NC + dir*2048 + r*64 + u*4);

  for (int s = 0; s < 256; ++s){
    int t = dir ? 255 - s : s;
    // prefetch next step's xW (hidden behind spin + MFMA phase)
    int sn = (s < 255) ? s + 1 : s;
    int tn = dir ? 255 - sn : sn;
    u16x4 nxt = *(const u16x4*)(xw + (size_t)(tn*32 + b)*NC + dir*2048 + r*64 + u*4);

    if (s > 0){
      if (tid == 0){
        while (__hip_atomic_load(&mycnt[s-1], __ATOMIC_RELAXED, __HIP_MEMORY_SCOPE_AGENT) < 32u) {}
        __threadfence();                       // acquire: L1/L2 inv before frag reads
      }
      __syncthreads();
    }

    // z = h_{s-1} @ U  (A-frags from global double-buffer, parity (s-1)&1)
    int pr = (s + 1) & 1;
    f32x4 acc0 = {0.f,0.f,0.f,0.f}, acc1 = {0.f,0.f,0.f,0.f};
    const u16* ab = hfg + (size_t)(pr*2)*16*512 + lane*8;
    #pragma unroll
    for (int i = 0; i < 8; i++){
      int ks = kh*8 + i;
      bf16x8 a0 = __builtin_bit_cast(bf16x8, *(const u16x8*)(ab + (size_t)ks*512));
      bf16x8 a1 = __builtin_bit_cast(bf16x8, *(const u16x8*)(ab + (size_t)(16 + ks)*512));
      acc0 = __builtin_amdgcn_mfma_f32_16x16x32_bf16(a0, bfr[i], acc0, 0, 0, 0);
      acc1 = __builtin_amdgcn_mfma_f32_16x16x32_bf16(a1, bfr[i], acc1, 0, 0, 0);
    }
    {
      int row0 = (lane >> 4)*4, cc = nw*16 + (lane & 15);
      #pragma unroll
      for (int v = 0; v < 4; v++){
        zbuf[kh][row0 + v][cc]      = acc0[v];
        zbuf[kh][16 + row0 + v][cc] = acc1[v];
      }
    }
    __syncthreads();

    // gate stage: thread (b,u)
    {
      f32x4 za = *(const f32x4*)&zbuf[0][b][u*4];
      f32x4 zc = *(const f32x4*)&zbuf[1][b][u*4];
      float zi = za[0] + zc[0] + bf2f(pref[0]);
      float zf = za[1] + zc[1] + bf2f(pref[1]);
      float zg = za[2] + zc[2] + bf2f(pref[2]);
      float zo = za[3] + zc[3] + bf2f(pref[3]);
      float gi = sigm(zi), gf = sigm(zf), gg = tanh_(zg), go = sigm(zo);
      float cn = gf*c_s[b][u] + gi*gg;
      float hn = go*tanh_(cn);
      if ((mk[b][t >> 5] >> (t & 31)) & 1){ c_s[b][u] = cn; h_s[b][u] = hn; }
      float hc = h_s[b][u];
      if (rep == (b >> 3)){                    // this replica writes this batch-quarter
        out[(size_t)(b*256 + t)*1024 + dir*512 + ug] = hc;
        if (s == 255){
          out[8388608 + dir*16384 + b*512 + ug] = hc;                 // h_f / h_b
          out[8388608 + 32768 + dir*16384 + b*512 + ug] = c_s[b][u];  // c_f / c_b
        }
      }
      // publish h_s as next step's A-fragment (parity s&1)
      int mt = b >> 4, ks2 = r >> 1, q = ((r & 1) << 1) | (u >> 3), j = u & 7;
      int lane2 = (q << 4) | (b & 15);
      hfg[(((size_t)(s & 1)*2 + mt)*16 + ks2)*512 + lane2*8 + j] = f2bf(hc);
      pref = nxt;
    }
    __syncthreads();                            // drains all waves' stores (vmcnt0 at barrier)
    if (tid == 0){ __threadfence(); atomicAdd(&mycnt[s], 1u); }   // release + arrive
  }
}

// ----------------------------------------------------------------------------
extern "C" void kernel_launch(void* const* d_in, const int* in_sizes, int n_in,
                              void* d_out, int out_size, void* d_ws, size_t ws_size,
                              hipStream_t stream){
  const int*   x   = (const int*)  d_in[0];
  const float* h0f = (const float*)d_in[1];
  const float* c0f = (const float*)d_in[2];
  const float* h0b = (const float*)d_in[3];
  const float* c0b = (const float*)d_in[4];
  const float* emb = (const float*)d_in[5];
  const float* Wf  = (const float*)d_in[6];
  const float* Uf  = (const float*)d_in[7];
  const float* bfv = (const float*)d_in[8];
  const float* Wb  = (const float*)d_in[9];
  const float* Ub  = (const float*)d_in[10];
  const float* bbv = (const float*)d_in[11];
  float* out = (float*)d_out;

  char* w = (char*)d_ws;
  u16*   aemb = (u16*)(w + OFF_AEMB);
  u16*   wpt  = (u16*)(w + OFF_WPT);
  float* bias = (float*)(w + OFF_BIAS);
  u16*   upt  = (u16*)(w + OFF_UPT);
  u32*   mskb = (u32*)(w + OFF_MASK);
  u16*   hfrg = (u16*)(w + OFF_HFRG);
  u32*   cnt  = (u32*)(w + OFF_CNT);
  u16*   xw   = (u16*)(w + OFF_XW);

  hipMemsetAsync(cnt, 0, 8*256*4, stream);
  k_prep_aemb<<<dim3(8192),  dim3(320), 0, stream>>>(x, emb, aemb);
  k_prep_wt  <<<dim3(64),    dim3(256), 0, stream>>>(Wf, Wb, bfv, bbv, wpt, bias);
  k_prep_ut  <<<dim3(128),   dim3(256), 0, stream>>>(Uf, Ub, upt);
  k_prep_misc<<<dim3(513),   dim3(256), 0, stream>>>(x, h0f, h0b, mskb, hfrg);
  k_ingemm   <<<dim3(64,64), dim3(512), 0, stream>>>(aemb, wpt, bias, xw);
  k_recur    <<<dim3(256),   dim3(512), 0, stream>>>(xw, upt, mskb, hfrg, cnt,
                                                     c0f, c0b, h0f, h0b, out);
}

// Round 2
// 2577.787 us; speedup vs baseline: 1.3603x; 1.3603x over previous
//
#include <hip/hip_runtime.h>

// ============================================================================
// Bidirectional LSTM encoder, MI355X.  R2: fence-free recurrence.
//   - h exchange + step flags via agent-scope RELAXED atomics (sc1, device-
//     coherent per access) -> no buffer_wbl2/buffer_inv in the step loop.
//   - per-wg flag slots polled by 32 lanes of wave0 (no contended RMW).
//   - 2 sync groups (fwd, bwd) x 32 wgs; replicas dropped.
//   - h/c state in registers; out-stores after the flag (off critical path).
// ============================================================================

typedef unsigned short u16;
typedef unsigned int   u32;
typedef u16   u16x8 __attribute__((ext_vector_type(8)));
typedef u16   u16x4 __attribute__((ext_vector_type(4)));
typedef __bf16 bf16x8 __attribute__((ext_vector_type(8)));
typedef float f32x4 __attribute__((ext_vector_type(4)));

#define EP 320            // padded E (300 -> 320)
#define NC 4096           // 2 dirs * 4H

static const size_t OFF_AEMB = 0;                              // 8192*320*2
static const size_t OFF_WPT  = OFF_AEMB + (size_t)8192*EP*2;
static const size_t OFF_BIAS = OFF_WPT  + (size_t)NC*EP*2;     // f32[4096]
static const size_t OFF_UPT  = OFF_BIAS + (size_t)NC*4;        // bf16 [4096][512]
static const size_t OFF_MASK = OFF_UPT  + (size_t)NC*512*2;    // u32 [32][8]
static const size_t OFF_HFRG = OFF_MASK + 1024;                // bf16 2grp*[2par][2mt][16ks][64][8]
static const size_t OFF_CNT  = OFF_HFRG + (size_t)2*32768*2;   // u32 [2][64] (padded)
static const size_t OFF_XW   = OFF_CNT  + 1024;                // bf16 [8192][4096]

__device__ __forceinline__ u16 f2bf(float f){               // RNE
  u32 u = __builtin_bit_cast(u32, f);
  return (u16)((u + 0x7FFFu + ((u >> 16) & 1u)) >> 16);
}
__device__ __forceinline__ float bf2f(u16 h){
  u32 u = ((u32)h) << 16; return __builtin_bit_cast(float, u);
}
__device__ __forceinline__ float sigm(float x){ return 1.f/(1.f+__expf(-x)); }
__device__ __forceinline__ float tanh_(float x){ return 2.f/(1.f+__expf(-2.f*x)) - 1.f; }

// ---------------------------------------------------------------- prep: A=emb gather
__global__ __launch_bounds__(320) void k_prep_aemb(const int* __restrict__ x,
                                                   const float* __restrict__ emb,
                                                   u16* __restrict__ aemb){
  int m = blockIdx.x;            // row = t*32 + b
  int k = threadIdx.x;
  int b = m & 31, t = m >> 5;
  int tok = x[b*256 + t];
  float v = (k < 300) ? emb[(size_t)tok*300 + k] : 0.f;
  aemb[(size_t)m*EP + k] = f2bf(v);
}

// ---------------------------------------------------------------- prep: W -> [col'][K] bf16 + bias
__global__ __launch_bounds__(256) void k_prep_wt(const float* __restrict__ Wf, const float* __restrict__ Wb,
                                                 const float* __restrict__ bfv, const float* __restrict__ bbv,
                                                 u16* __restrict__ wpt, float* __restrict__ bias){
  __shared__ u16 lds[320][64];
  int bid = blockIdx.x, tid = threadIdx.x;   // 64 wgs
  int c0 = bid*64; int dir = c0 >> 11;
  const float* W = dir ? Wb : Wf;
  int cl = tid & 63, rr = tid >> 6;
  int ci = (c0 + cl) & 2047; int srccol = (ci & 3)*512 + (ci >> 2);   // col' = u*4+g  <- g*512+u
  for (int kk = 0; kk < 80; kk++){
    int row = kk*4 + rr;
    float v = (row < 300) ? W[(size_t)row*2048 + srccol] : 0.f;
    lds[row][cl] = f2bf(v);
  }
  __syncthreads();
  int cw = tid >> 2, kc = tid & 3;
  #pragma unroll
  for (int j = 0; j < 10; j++){
    u16x8 v;
    #pragma unroll
    for (int e = 0; e < 8; e++) v[e] = lds[kc*80 + j*8 + e][cw];
    *(u16x8*)&wpt[(size_t)(c0+cw)*EP + kc*80 + j*8] = v;
  }
  if (tid < 64){
    int ci2 = (c0 + tid) & 2047; int sc = (ci2 & 3)*512 + (ci2 >> 2);
    bias[c0 + tid] = (dir ? bbv : bfv)[sc];
  }
}

// ---------------------------------------------------------------- prep: U -> [col'][K] bf16
__global__ __launch_bounds__(256) void k_prep_ut(const float* __restrict__ Uf, const float* __restrict__ Ub,
                                                 u16* __restrict__ upt){
  __shared__ u16 lds[512][32];
  int bid = blockIdx.x, tid = threadIdx.x;   // 128 wgs
  int cg0 = bid*32; int dir = cg0 >> 11;
  const float* U = dir ? Ub : Uf;
  int cl = tid & 31, rr = tid >> 5;
  int ci = (cg0 + cl) & 2047; int srccol = (ci & 3)*512 + (ci >> 2);
  for (int kk = 0; kk < 64; kk++){
    int row = kk*8 + rr;
    lds[row][cl] = f2bf(U[(size_t)row*2048 + srccol]);
  }
  __syncthreads();
  int cw = tid >> 3, kc = tid & 7;
  #pragma unroll
  for (int j = 0; j < 8; j++){
    u16x8 v;
    #pragma unroll
    for (int e = 0; e < 8; e++) v[e] = lds[kc*64 + j*8 + e][cw];
    *(u16x8*)&upt[(size_t)(cg0+cw)*512 + kc*64 + j*8] = v;
  }
}

// ---------------------------------------------------------------- prep: mask bitmap + h0 frag image
__global__ __launch_bounds__(256) void k_prep_misc(const int* __restrict__ x,
                                                   const float* __restrict__ h0f, const float* __restrict__ h0b,
                                                   u32* __restrict__ maskb, u16* __restrict__ hfrag){
  int bid = blockIdx.x, tid = threadIdx.x;
  if (bid == 128){
    int b = tid >> 3, w = tid & 7;
    u32 m = 0;
    for (int i = 0; i < 32; i++){ int t = w*32 + i; m |= (u32)(x[b*256 + t] != 0) << i; }
    maskb[b*8 + w] = m;
    return;
  }
  int idx = bid*256 + tid;                      // 0 .. 32767
  int grp = idx >> 14, rem = idx & 16383, b = rem >> 9, ug = rem & 511;
  const float* h0 = grp ? h0b : h0f;
  u16 val = f2bf(h0[b*512 + ug]);
  int mt = b >> 4, ks = ug >> 5, q = (ug >> 3) & 3, j = ug & 7, lane = q*16 + (b & 15);
  // parity 1 holds h_{-1}
  hfrag[(size_t)grp*32768 + ((size_t)(2 + mt)*16 + ks)*512 + lane*8 + j] = val;
}

// ---------------------------------------------------------------- input GEMM: xW+b (bf16 MFMA)
__global__ __launch_bounds__(512) void k_ingemm(const u16* __restrict__ aemb, const u16* __restrict__ wpt,
                                                const float* __restrict__ bias, u16* __restrict__ xw){
  int bx = blockIdx.x, by = blockIdx.y;        // 64 x 64
  int tid = threadIdx.x, lane = tid & 63, wv = tid >> 6;
  int m0 = bx*128 + wv*16;
  u16x8 afr[10];
  const u16* ap = aemb + (size_t)(m0 + (lane & 15))*EP + ((lane >> 4)*8);
  #pragma unroll
  for (int ks = 0; ks < 10; ks++) afr[ks] = *(const u16x8*)(ap + ks*32);
  #pragma unroll
  for (int n = 0; n < 4; n++){
    int colp = by*64 + n*16 + (lane & 15);
    const u16* bp = wpt + (size_t)colp*EP + ((lane >> 4)*8);
    f32x4 acc = {0.f, 0.f, 0.f, 0.f};
    #pragma unroll
    for (int ks = 0; ks < 10; ks++){
      bf16x8 bfr = __builtin_bit_cast(bf16x8, *(const u16x8*)(bp + ks*32));
      acc = __builtin_amdgcn_mfma_f32_16x16x32_bf16(__builtin_bit_cast(bf16x8, afr[ks]), bfr, acc, 0, 0, 0);
    }
    float bv = bias[colp];
    #pragma unroll
    for (int v = 0; v < 4; v++){
      int m = m0 + (lane >> 4)*4 + v;          // C/D: col=lane&15, row=(lane>>4)*4+reg  [m89]
      xw[(size_t)m*NC + colp] = f2bf(acc[v] + bv);
    }
  }
}

// ---------------------------------------------------------------- persistent recurrence (fence-free)
__global__ __launch_bounds__(512) void k_recur(const u16* __restrict__ xw, const u16* __restrict__ upt,
                                               const u32* __restrict__ maskb, u16* __restrict__ hfrag,
                                               u32* __restrict__ cnt,
                                               const float* __restrict__ c0f, const float* __restrict__ c0b,
                                               const float* __restrict__ h0f, const float* __restrict__ h0b,
                                               float* __restrict__ out){
  int bid = blockIdx.x;
  int dir = bid & 1, r = bid >> 1;             // direction, rank in group (0..31)
  int tid = threadIdx.x, lane = tid & 63, wv = tid >> 6;
  int nw = wv & 3, kh = wv >> 2;               // wave's N-tile (of 4) and K-half

  __shared__ float zbuf[2][32][64];            // [khalf][b][local col]
  __shared__ u32 mk[32][8];

  // U-slice as persistent B-fragments in registers (col = r*64 + nw*16 + lane&15)
  bf16x8 bfr[8];
  {
    const u16* ub = upt + ((size_t)dir*2048 + r*64 + nw*16 + (lane & 15))*512 + ((lane >> 4)*8);
    #pragma unroll
    for (int i = 0; i < 8; i++){ int ks = kh*8 + i; bfr[i] = __builtin_bit_cast(bf16x8, *(const u16x8*)(ub + ks*32)); }
  }
  int b = tid >> 4, u = tid & 15, ug = r*16 + u;
  float c_reg = (dir ? c0b : c0f)[b*512 + ug];
  float h_reg = (dir ? h0b : h0f)[b*512 + ug];
  if (tid < 256) mk[tid >> 3][tid & 7] = maskb[tid];

  u16* hfg = hfrag + (size_t)dir*32768;
  u32* flg = cnt + dir*64;
  const u32* abase = (const u32*)hfg;
  __syncthreads();

  int t0 = dir ? 255 : 0;
  u16x4 pref = *(const u16x4*)(xw + (size_t)(t0*32 + b)*NC + dir*2048 + r*64 + u*4);

  for (int s = 0; s < 256; ++s){
    int t = dir ? 255 - s : s;
    int sn = (s < 255) ? s + 1 : s;
    int tn = dir ? 255 - sn : sn;
    u16x4 nxt = *(const u16x4*)(xw + (size_t)(tn*32 + b)*NC + dir*2048 + r*64 + u*4);

    if (s > 0){
      if (wv == 0){                            // 32 lanes poll 32 per-wg flags in parallel
        u32 need = (u32)s, v;
        do {
          v = (lane < 32) ? __hip_atomic_load(&flg[lane], __ATOMIC_RELAXED, __HIP_MEMORY_SCOPE_AGENT)
                          : need;
        } while (__any(v < need));
      }
      __syncthreads();
    }

    // z = h_{s-1} @ U : A-frags via agent-scope dword loads (coherent, no fences)
    int pr = (s + 1) & 1;
    size_t base = (size_t)pr*8192 + (size_t)lane*4;   // dword units
    u32 aw[16][4];
    #pragma unroll
    for (int i = 0; i < 8; i++){
      int ks = kh*8 + i;
      #pragma unroll
      for (int d = 0; d < 4; d++){
        aw[i][d]   = __hip_atomic_load(abase + base + (size_t)ks*256 + d,      __ATOMIC_RELAXED, __HIP_MEMORY_SCOPE_AGENT);
        aw[8+i][d] = __hip_atomic_load(abase + base + (size_t)(16+ks)*256 + d, __ATOMIC_RELAXED, __HIP_MEMORY_SCOPE_AGENT);
      }
    }
    f32x4 acc0 = {0.f,0.f,0.f,0.f}, acc1 = {0.f,0.f,0.f,0.f};
    #pragma unroll
    for (int i = 0; i < 8; i++){
      union { u32 w[4]; bf16x8 v; } ua, ub2;
      #pragma unroll
      for (int d = 0; d < 4; d++){ ua.w[d] = aw[i][d]; ub2.w[d] = aw[8+i][d]; }
      acc0 = __builtin_amdgcn_mfma_f32_16x16x32_bf16(ua.v,  bfr[i], acc0, 0, 0, 0);
      acc1 = __builtin_amdgcn_mfma_f32_16x16x32_bf16(ub2.v, bfr[i], acc1, 0, 0, 0);
    }
    {
      int row0 = (lane >> 4)*4, cc = nw*16 + (lane & 15);
      #pragma unroll
      for (int v = 0; v < 4; v++){
        zbuf[kh][row0 + v][cc]      = acc0[v];
        zbuf[kh][16 + row0 + v][cc] = acc1[v];
      }
    }
    __syncthreads();

    // gate stage: thread (b,u)
    f32x4 za = *(const f32x4*)&zbuf[0][b][u*4];
    f32x4 zc = *(const f32x4*)&zbuf[1][b][u*4];
    float zi = za[0] + zc[0] + bf2f(pref[0]);
    float zf = za[1] + zc[1] + bf2f(pref[1]);
    float zg = za[2] + zc[2] + bf2f(pref[2]);
    float zo = za[3] + zc[3] + bf2f(pref[3]);
    float gi = sigm(zi), gf = sigm(zf), gg = tanh_(zg), go = sigm(zo);
    float cn = gf*c_reg + gi*gg;
    float hn = go*tanh_(cn);
    if ((mk[b][t >> 5] >> (t & 31)) & 1){ c_reg = cn; h_reg = hn; }
    float hc = h_reg;

    // publish h as next step's A-fragment (parity s&1): packed dword sc1 stores
    float ho = __shfl_xor(hc, 1);
    if (!(u & 1)){
      u32 dw = (u32)f2bf(hc) | ((u32)f2bf(ho) << 16);
      int mt = b >> 4, ks2 = r >> 1, q = ((r & 1) << 1) | (u >> 3), j = u & 7;
      int lane2 = (q << 4) | (b & 15);
      size_t u16idx = (((size_t)(s & 1)*2 + mt)*16 + ks2)*512 + lane2*8 + j;
      __hip_atomic_store((u32*)hfg + (u16idx >> 1), dw, __ATOMIC_RELAXED, __HIP_MEMORY_SCOPE_AGENT);
    }
    asm volatile("s_waitcnt vmcnt(0)" ::: "memory");   // publish acked at coherence point
    __syncthreads();                                    // all waves' publishes done
    if (tid == 0 && s < 255)
      __hip_atomic_store(&flg[r], (u32)(s + 1), __ATOMIC_RELAXED, __HIP_MEMORY_SCOPE_AGENT);

    // out-stores off the critical path (overlap with other wgs' polling)
    out[(size_t)(b*256 + t)*1024 + dir*512 + ug] = hc;
    if (s == 255){
      out[8388608 + dir*16384 + b*512 + ug] = hc;                 // h_f / h_b
      out[8388608 + 32768 + dir*16384 + b*512 + ug] = c_reg;      // c_f / c_b
    }
    pref = nxt;
  }
}

// ----------------------------------------------------------------------------
extern "C" void kernel_launch(void* const* d_in, const int* in_sizes, int n_in,
                              void* d_out, int out_size, void* d_ws, size_t ws_size,
                              hipStream_t stream){
  const int*   x   = (const int*)  d_in[0];
  const float* h0f = (const float*)d_in[1];
  const float* c0f = (const float*)d_in[2];
  const float* h0b = (const float*)d_in[3];
  const float* c0b = (const float*)d_in[4];
  const float* emb = (const float*)d_in[5];
  const float* Wf  = (const float*)d_in[6];
  const float* Uf  = (const float*)d_in[7];
  const float* bfv = (const float*)d_in[8];
  const float* Wb  = (const float*)d_in[9];
  const float* Ub  = (const float*)d_in[10];
  const float* bbv = (const float*)d_in[11];
  float* out = (float*)d_out;

  char* w = (char*)d_ws;
  u16*   aemb = (u16*)(w + OFF_AEMB);
  u16*   wpt  = (u16*)(w + OFF_WPT);
  float* bias = (float*)(w + OFF_BIAS);
  u16*   upt  = (u16*)(w + OFF_UPT);
  u32*   mskb = (u32*)(w + OFF_MASK);
  u16*   hfrg = (u16*)(w + OFF_HFRG);
  u32*   cnt  = (u32*)(w + OFF_CNT);
  u16*   xw   = (u16*)(w + OFF_XW);

  hipMemsetAsync(cnt, 0, 1024, stream);
  k_prep_aemb<<<dim3(8192),  dim3(320), 0, stream>>>(x, emb, aemb);
  k_prep_wt  <<<dim3(64),    dim3(256), 0, stream>>>(Wf, Wb, bfv, bbv, wpt, bias);
  k_prep_ut  <<<dim3(128),   dim3(256), 0, stream>>>(Uf, Ub, upt);
  k_prep_misc<<<dim3(129),   dim3(256), 0, stream>>>(x, h0f, h0b, mskb, hfrg);
  k_ingemm   <<<dim3(64,64), dim3(512), 0, stream>>>(aemb, wpt, bias, xw);
  k_recur    <<<dim3(64),    dim3(512), 0, stream>>>(xw, upt, mskb, hfrg, cnt,
                                                     c0f, c0b, h0f, h0b, out);
}

// Round 3
// 1010.296 us; speedup vs baseline: 3.4708x; 2.5515x over previous
//
#include <hip/hip_runtime.h>

// ============================================================================
// Bidirectional LSTM encoder, MI355X.  R3: minimal coherent-op recurrence.
//   - h image staged to LDS via 4x global_load_dwordx4 sc0 sc1 per thread
//     (32 coherent load instrs/CU/step, was 512 scalar ones, 4x redundant).
//   - publish = 1 coalesced global_store_dwordx4 sc0 sc1 by wave0 from a
//     1KB LDS tile shaped as the wg's contiguous frag-image blocks.
//   - per-wg flag slots (agent relaxed atomics) polled by 32 lanes of wave0.
// ============================================================================

typedef unsigned short u16;
typedef unsigned int   u32;
typedef u16   u16x8 __attribute__((ext_vector_type(8)));
typedef u16   u16x4 __attribute__((ext_vector_type(4)));
typedef u32   u32x4 __attribute__((ext_vector_type(4)));
typedef __bf16 bf16x8 __attribute__((ext_vector_type(8)));
typedef float f32x4 __attribute__((ext_vector_type(4)));

#define EP 320            // padded E (300 -> 320)
#define NC 4096           // 2 dirs * 4H

static const size_t OFF_AEMB = 0;                              // 8192*320*2
static const size_t OFF_WPT  = OFF_AEMB + (size_t)8192*EP*2;
static const size_t OFF_BIAS = OFF_WPT  + (size_t)NC*EP*2;     // f32[4096]
static const size_t OFF_UPT  = OFF_BIAS + (size_t)NC*4;        // bf16 [4096][512]
static const size_t OFF_MASK = OFF_UPT  + (size_t)NC*512*2;    // u32 [32][8]
static const size_t OFF_HFRG = OFF_MASK + 1024;                // bf16 2grp*[2par][2mt][16ks][64][8]
static const size_t OFF_CNT  = OFF_HFRG + (size_t)2*32768*2;   // u32 [2][64]
static const size_t OFF_XW   = OFF_CNT  + 1024;                // bf16 [8192][4096]

__device__ __forceinline__ u16 f2bf(float f){               // RNE
  u32 u = __builtin_bit_cast(u32, f);
  return (u16)((u + 0x7FFFu + ((u >> 16) & 1u)) >> 16);
}
__device__ __forceinline__ float bf2f(u16 h){
  u32 u = ((u32)h) << 16; return __builtin_bit_cast(float, u);
}
__device__ __forceinline__ float sigm(float x){ return 1.f/(1.f+__expf(-x)); }
__device__ __forceinline__ float tanh_(float x){ return 2.f/(1.f+__expf(-2.f*x)) - 1.f; }

// ---------------------------------------------------------------- prep: A=emb gather
__global__ __launch_bounds__(320) void k_prep_aemb(const int* __restrict__ x,
                                                   const float* __restrict__ emb,
                                                   u16* __restrict__ aemb){
  int m = blockIdx.x;            // row = t*32 + b
  int k = threadIdx.x;
  int b = m & 31, t = m >> 5;
  int tok = x[b*256 + t];
  float v = (k < 300) ? emb[(size_t)tok*300 + k] : 0.f;
  aemb[(size_t)m*EP + k] = f2bf(v);
}

// ---------------------------------------------------------------- prep: W -> [col'][K] bf16 + bias
__global__ __launch_bounds__(256) void k_prep_wt(const float* __restrict__ Wf, const float* __restrict__ Wb,
                                                 const float* __restrict__ bfv, const float* __restrict__ bbv,
                                                 u16* __restrict__ wpt, float* __restrict__ bias){
  __shared__ u16 lds[320][64];
  int bid = blockIdx.x, tid = threadIdx.x;   // 64 wgs
  int c0 = bid*64; int dir = c0 >> 11;
  const float* W = dir ? Wb : Wf;
  int cl = tid & 63, rr = tid >> 6;
  int ci = (c0 + cl) & 2047; int srccol = (ci & 3)*512 + (ci >> 2);   // col' = u*4+g  <- g*512+u
  for (int kk = 0; kk < 80; kk++){
    int row = kk*4 + rr;
    float v = (row < 300) ? W[(size_t)row*2048 + srccol] : 0.f;
    lds[row][cl] = f2bf(v);
  }
  __syncthreads();
  int cw = tid >> 2, kc = tid & 3;
  #pragma unroll
  for (int j = 0; j < 10; j++){
    u16x8 v;
    #pragma unroll
    for (int e = 0; e < 8; e++) v[e] = lds[kc*80 + j*8 + e][cw];
    *(u16x8*)&wpt[(size_t)(c0+cw)*EP + kc*80 + j*8] = v;
  }
  if (tid < 64){
    int ci2 = (c0 + tid) & 2047; int sc = (ci2 & 3)*512 + (ci2 >> 2);
    bias[c0 + tid] = (dir ? bbv : bfv)[sc];
  }
}

// ---------------------------------------------------------------- prep: U -> [col'][K] bf16
__global__ __launch_bounds__(256) void k_prep_ut(const float* __restrict__ Uf, const float* __restrict__ Ub,
                                                 u16* __restrict__ upt){
  __shared__ u16 lds[512][32];
  int bid = blockIdx.x, tid = threadIdx.x;   // 128 wgs
  int cg0 = bid*32; int dir = cg0 >> 11;
  const float* U = dir ? Ub : Uf;
  int cl = tid & 31, rr = tid >> 5;
  int ci = (cg0 + cl) & 2047; int srccol = (ci & 3)*512 + (ci >> 2);
  for (int kk = 0; kk < 64; kk++){
    int row = kk*8 + rr;
    lds[row][cl] = f2bf(U[(size_t)row*2048 + srccol]);
  }
  __syncthreads();
  int cw = tid >> 3, kc = tid & 7;
  #pragma unroll
  for (int j = 0; j < 8; j++){
    u16x8 v;
    #pragma unroll
    for (int e = 0; e < 8; e++) v[e] = lds[kc*64 + j*8 + e][cw];
    *(u16x8*)&upt[(size_t)(cg0+cw)*512 + kc*64 + j*8] = v;
  }
}

// ---------------------------------------------------------------- prep: mask bitmap + h0 frag image
__global__ __launch_bounds__(256) void k_prep_misc(const int* __restrict__ x,
                                                   const float* __restrict__ h0f, const float* __restrict__ h0b,
                                                   u32* __restrict__ maskb, u16* __restrict__ hfrag){
  int bid = blockIdx.x, tid = threadIdx.x;
  if (bid == 128){
    int b = tid >> 3, w = tid & 7;
    u32 m = 0;
    for (int i = 0; i < 32; i++){ int t = w*32 + i; m |= (u32)(x[b*256 + t] != 0) << i; }
    maskb[b*8 + w] = m;
    return;
  }
  int idx = bid*256 + tid;                      // 0 .. 32767
  int grp = idx >> 14, rem = idx & 16383, b = rem >> 9, ug = rem & 511;
  const float* h0 = grp ? h0b : h0f;
  u16 val = f2bf(h0[b*512 + ug]);
  int mt = b >> 4, ks = ug >> 5, q = (ug >> 3) & 3, j = ug & 7, lane = q*16 + (b & 15);
  // parity 1 holds h_{-1}
  hfrag[(size_t)grp*32768 + ((size_t)(2 + mt)*16 + ks)*512 + lane*8 + j] = val;
}

// ---------------------------------------------------------------- input GEMM: xW+b (bf16 MFMA)
__global__ __launch_bounds__(512) void k_ingemm(const u16* __restrict__ aemb, const u16* __restrict__ wpt,
                                                const float* __restrict__ bias, u16* __restrict__ xw){
  int bx = blockIdx.x, by = blockIdx.y;        // 64 x 64
  int tid = threadIdx.x, lane = tid & 63, wv = tid >> 6;
  int m0 = bx*128 + wv*16;
  u16x8 afr[10];
  const u16* ap = aemb + (size_t)(m0 + (lane & 15))*EP + ((lane >> 4)*8);
  #pragma unroll
  for (int ks = 0; ks < 10; ks++) afr[ks] = *(const u16x8*)(ap + ks*32);
  #pragma unroll
  for (int n = 0; n < 4; n++){
    int colp = by*64 + n*16 + (lane & 15);
    const u16* bp = wpt + (size_t)colp*EP + ((lane >> 4)*8);
    f32x4 acc = {0.f, 0.f, 0.f, 0.f};
    #pragma unroll
    for (int ks = 0; ks < 10; ks++){
      bf16x8 bfr = __builtin_bit_cast(bf16x8, *(const u16x8*)(bp + ks*32));
      acc = __builtin_amdgcn_mfma_f32_16x16x32_bf16(__builtin_bit_cast(bf16x8, afr[ks]), bfr, acc, 0, 0, 0);
    }
    float bv = bias[colp];
    #pragma unroll
    for (int v = 0; v < 4; v++){
      int m = m0 + (lane >> 4)*4 + v;          // C/D: col=lane&15, row=(lane>>4)*4+reg  [m89]
      xw[(size_t)m*NC + colp] = f2bf(acc[v] + bv);
    }
  }
}

// ---------------------------------------------------------------- persistent recurrence
__global__ __launch_bounds__(512) void k_recur(const u16* __restrict__ xw, const u16* __restrict__ upt,
                                               const u32* __restrict__ maskb, u16* __restrict__ hfrag,
                                               u32* __restrict__ cnt,
                                               const float* __restrict__ c0f, const float* __restrict__ c0b,
                                               const float* __restrict__ h0f, const float* __restrict__ h0b,
                                               float* __restrict__ out){
  int bid = blockIdx.x;
  int dir = bid & 1, r = bid >> 1;             // direction, rank in group (0..31)
  int tid = threadIdx.x, lane = tid & 63, wv = tid >> 6;
  int nw = wv & 3, kh = wv >> 2;               // wave's N-tile (of 4) and K-half

  __shared__ u16   astage[16384];              // one parity image: [mt][ks][lane*8+j], 32 KB
  __shared__ float zbuf[2][32][64];            // [khalf][b][local col], 16 KB
  __shared__ u16   hpub[512];                  // wg's publish tile: [mt][lsub][j], 1 KB
  __shared__ u32   mk[32][8];

  // U-slice as persistent B-fragments in registers (col = r*64 + nw*16 + lane&15)
  bf16x8 bfr[8];
  {
    const u16* ub = upt + ((size_t)dir*2048 + r*64 + nw*16 + (lane & 15))*512 + ((lane >> 4)*8);
    #pragma unroll
    for (int i = 0; i < 8; i++){ int ks = kh*8 + i; bfr[i] = __builtin_bit_cast(bf16x8, *(const u16x8*)(ub + ks*32)); }
  }
  int b = tid >> 4, u = tid & 15, ug = r*16 + u;
  float c_reg = (dir ? c0b : c0f)[b*512 + ug];
  float h_reg = (dir ? h0b : h0f)[b*512 + ug];
  if (tid < 256) mk[tid >> 3][tid & 7] = maskb[tid];

  u16* hfg = hfrag + (size_t)dir*32768;
  u32* flg = cnt + dir*64;
  __syncthreads();

  int t0 = dir ? 255 : 0;
  u16x4 pref = *(const u16x4*)(xw + (size_t)(t0*32 + b)*NC + dir*2048 + r*64 + u*4);

  int ks2 = r >> 1, q0 = (r & 1)*2;

  for (int s = 0; s < 256; ++s){
    int t = dir ? 255 - s : s;
    int sn = (s < 255) ? s + 1 : s;
    int tn = dir ? 255 - sn : sn;
    u16x4 nxt = *(const u16x4*)(xw + (size_t)(tn*32 + b)*NC + dir*2048 + r*64 + u*4);

    if (s > 0){
      if (wv == 0){                            // 32 lanes poll 32 per-wg flags in parallel
        u32 need = (u32)s, v;
        do {
          v = (lane < 32) ? __hip_atomic_load(&flg[lane], __ATOMIC_RELAXED, __HIP_MEMORY_SCOPE_AGENT)
                          : need;
        } while (__any(v < need));
      }
      __syncthreads();                         // (A) h image for this step is published
    }

    // ---- stage h image (parity (s+1)&1) into LDS: 4 coherent dwordx4 per thread
    {
      int pr = (s + 1) & 1;
      const char* gsrc = (const char*)hfg + (size_t)pr*32768 + (size_t)tid*16;
      u32x4 q0v, q1v, q2v, q3v;
      asm volatile("global_load_dwordx4 %0, %1, off sc0 sc1" : "=&v"(q0v) : "v"(gsrc));
      asm volatile("global_load_dwordx4 %0, %1, off sc0 sc1" : "=&v"(q1v) : "v"(gsrc + 8192));
      asm volatile("global_load_dwordx4 %0, %1, off sc0 sc1" : "=&v"(q2v) : "v"(gsrc + 16384));
      asm volatile("global_load_dwordx4 %0, %1, off sc0 sc1" : "=&v"(q3v) : "v"(gsrc + 24576));
      asm volatile("s_waitcnt vmcnt(0)" ::: "memory");
      u32x4* dst = (u32x4*)((char*)astage + tid*16);
      dst[0]    = q0v;                          // tid*16 + k*8192 bytes
      dst[512]  = q1v;                          // 8192 B / 16 = 512 u32x4
      dst[1024] = q2v;
      dst[1536] = q3v;
    }
    __syncthreads();                            // (B) astage ready

    // ---- z = h_{s-1} @ U from LDS frags
    f32x4 acc0 = {0.f,0.f,0.f,0.f}, acc1 = {0.f,0.f,0.f,0.f};
    {
      const u16* ab = astage + lane*8;
      #pragma unroll
      for (int i = 0; i < 8; i++){
        int ks = kh*8 + i;
        bf16x8 a0 = __builtin_bit_cast(bf16x8, *(const u16x8*)(ab + (size_t)ks*512));
        bf16x8 a1 = __builtin_bit_cast(bf16x8, *(const u16x8*)(ab + (size_t)(16 + ks)*512));
        acc0 = __builtin_amdgcn_mfma_f32_16x16x32_bf16(a0, bfr[i], acc0, 0, 0, 0);
        acc1 = __builtin_amdgcn_mfma_f32_16x16x32_bf16(a1, bfr[i], acc1, 0, 0, 0);
      }
      int row0 = (lane >> 4)*4, cc = nw*16 + (lane & 15);
      #pragma unroll
      for (int v = 0; v < 4; v++){
        zbuf[kh][row0 + v][cc]      = acc0[v];
        zbuf[kh][16 + row0 + v][cc] = acc1[v];
      }
    }
    __syncthreads();                            // (C) zbuf ready

    // ---- gate stage: thread (b,u)
    f32x4 za = *(const f32x4*)&zbuf[0][b][u*4];
    f32x4 zc = *(const f32x4*)&zbuf[1][b][u*4];
    float zi = za[0] + zc[0] + bf2f(pref[0]);
    float zf = za[1] + zc[1] + bf2f(pref[1]);
    float zg = za[2] + zc[2] + bf2f(pref[2]);
    float zo = za[3] + zc[3] + bf2f(pref[3]);
    float gi = sigm(zi), gf = sigm(zf), gg = tanh_(zg), go = sigm(zo);
    float cn = gf*c_reg + gi*gg;
    float hn = go*tanh_(cn);
    if ((mk[b][t >> 5] >> (t & 31)) & 1){ c_reg = cn; h_reg = hn; }
    float hc = h_reg;

    // h -> publish staging tile: [mt][(u>>3)*16 + (b&15)][u&7]
    hpub[((b >> 4)*32 + (u >> 3)*16 + (b & 15))*8 + (u & 7)] = f2bf(hc);
    __syncthreads();                            // (D) hpub ready

    if (wv == 0){
      // one coalesced coherent store: lane l -> mt=l>>5, lsub=l&31
      int mt = lane >> 5, lsub = lane & 31;
      u32x4 val = *(const u32x4*)((const char*)hpub + mt*512 + lsub*16);
      char* gdst = (char*)hfg + (((size_t)((s & 1)*2 + mt)*16 + ks2)*512 + (size_t)(q0*16 + lsub)*8)*2;
      asm volatile("global_store_dwordx4 %0, %1, off sc0 sc1" :: "v"(gdst), "v"(val) : "memory");
      asm volatile("s_waitcnt vmcnt(0)" ::: "memory");
      if (lane == 0 && s < 255)
        __hip_atomic_store(&flg[r], (u32)(s + 1), __ATOMIC_RELAXED, __HIP_MEMORY_SCOPE_AGENT);
    }

    // out-stores off the critical path
    out[(size_t)(b*256 + t)*1024 + dir*512 + ug] = hc;
    if (s == 255){
      out[8388608 + dir*16384 + b*512 + ug] = hc;                 // h_f / h_b
      out[8388608 + 32768 + dir*16384 + b*512 + ug] = c_reg;      // c_f / c_b
    }
    pref = nxt;
  }
}

// ----------------------------------------------------------------------------
extern "C" void kernel_launch(void* const* d_in, const int* in_sizes, int n_in,
                              void* d_out, int out_size, void* d_ws, size_t ws_size,
                              hipStream_t stream){
  const int*   x   = (const int*)  d_in[0];
  const float* h0f = (const float*)d_in[1];
  const float* c0f = (const float*)d_in[2];
  const float* h0b = (const float*)d_in[3];
  const float* c0b = (const float*)d_in[4];
  const float* emb = (const float*)d_in[5];
  const float* Wf  = (const float*)d_in[6];
  const float* Uf  = (const float*)d_in[7];
  const float* bfv = (const float*)d_in[8];
  const float* Wb  = (const float*)d_in[9];
  const float* Ub  = (const float*)d_in[10];
  const float* bbv = (const float*)d_in[11];
  float* out = (float*)d_out;

  char* w = (char*)d_ws;
  u16*   aemb = (u16*)(w + OFF_AEMB);
  u16*   wpt  = (u16*)(w + OFF_WPT);
  float* bias = (float*)(w + OFF_BIAS);
  u16*   upt  = (u16*)(w + OFF_UPT);
  u32*   mskb = (u32*)(w + OFF_MASK);
  u16*   hfrg = (u16*)(w + OFF_HFRG);
  u32*   cnt  = (u32*)(w + OFF_CNT);
  u16*   xw   = (u16*)(w + OFF_XW);

  hipMemsetAsync(cnt, 0, 1024, stream);
  k_prep_aemb<<<dim3(8192),  dim3(320), 0, stream>>>(x, emb, aemb);
  k_prep_wt  <<<dim3(64),    dim3(256), 0, stream>>>(Wf, Wb, bfv, bbv, wpt, bias);
  k_prep_ut  <<<dim3(128),   dim3(256), 0, stream>>>(Uf, Ub, upt);
  k_prep_misc<<<dim3(129),   dim3(256), 0, stream>>>(x, h0f, h0b, mskb, hfrg);
  k_ingemm   <<<dim3(64,64), dim3(512), 0, stream>>>(aemb, wpt, bias, xw);
  k_recur    <<<dim3(64),    dim3(512), 0, stream>>>(xw, upt, mskb, hfrg, cnt,
                                                     c0f, c0b, h0f, h0b, out);
}